// Round 11
// baseline (276.731 us; speedup 1.0000x reference)
//
#include <hip/hip_runtime.h>
#include <hip/hip_bf16.h>
#include <stdint.h>
#include <math.h>

namespace {

constexpr int kB = 2;
constexpr int kN = 2048;
constexpr int kC = 1024;
constexpr int kH = 16;
constexpr int kD = 64;
constexpr int kTok = kB * kN;               // 4096
constexpr int k3C  = 3 * kC;                // 3072
constexpr size_t kPS = (size_t)kTok * k3C;  // qkv plane elems
constexpr size_t kXE = (size_t)kTok * kC;   // x / VT plane elems
constexpr size_t kWQ = (size_t)k3C * kC;    // qkv_w elems
constexpr size_t kWP = (size_t)kC * kC;     // proj_w elems

using bhalf8 = __attribute__((ext_vector_type(8))) __bf16;
using f32x4  = __attribute__((ext_vector_type(4))) float;

__device__ inline unsigned short f2bf(float f) {
  __hip_bfloat16 h = __float2bfloat16(f);
  return *reinterpret_cast<unsigned short*>(&h);
}
__device__ inline float bf2f(unsigned short u) {
  __hip_bfloat16 h;
  *reinterpret_cast<unsigned short*>(&h) = u;
  return __bfloat162float(h);
}
__device__ inline void split2(float v, unsigned short& h, unsigned short& l) {
  const unsigned short hb = f2bf(v);
  h = hb;
  l = f2bf(v - bf2f(hb));
}

// raw hardware 2^x (compiler-managed TRANS hazards). Verified round 7:
// libm exp2f's OCML path cost +10pt VALUBusy / +10us on attn.
#if __has_builtin(__builtin_amdgcn_exp2f)
__device__ inline float fexp2(float x) { return __builtin_amdgcn_exp2f(x); }
#else
__device__ inline float fexp2(float x) { return __expf(x * 0.6931471805599453f); }
#endif

// async global->LDS, 16B per lane; LDS dest must be wave-uniform base + lane*16
__device__ inline void glds16(const unsigned short* g, unsigned short* l) {
  __builtin_amdgcn_global_load_lds(
      (const __attribute__((address_space(1))) void*)g,
      (__attribute__((address_space(3))) void*)l, 16, 0, 0);
}

__device__ inline void split4(const float4 v, ushort4& hh, ushort4& ll) {
  split2(v.x, hh.x, ll.x); split2(v.y, hh.y, ll.y);
  split2(v.z, hh.z, ll.z); split2(v.w, hh.w, ll.w);
}

// ---- fused prep: split x AND qkv_w fp32 -> bf16 hi/lo planes (1 launch) ----
__global__ __launch_bounds__(256)
void prep_split(const float* __restrict__ x, const float* __restrict__ wq,
                unsigned short* __restrict__ xH, unsigned short* __restrict__ xL,
                unsigned short* __restrict__ wqH, unsigned short* __restrict__ wqL)
{
  constexpr int nX = (int)(kXE / 4);       // 1048576 f4 units (4096 blocks)
  int i = blockIdx.x * 256 + threadIdx.x;
  const float* src;
  unsigned short *H, *L;
  if (i < nX) { src = x;  H = xH;  L = xL; }
  else        { i -= nX; src = wq; H = wqH; L = wqL; }
  const float4 v = ((const float4*)src)[i];
  ushort4 hh, ll;
  split4(v, hh, ll);
  ((ushort4*)H)[i] = hh;
  ((ushort4*)L)[i] = ll;
}

// ---- fused: V^T pre-transpose (blocks 0..2047) + proj_w split (2048..3071) ----
__global__ __launch_bounds__(256)
void vt_and_split(const unsigned short* __restrict__ H,
                  unsigned short* __restrict__ VTH,
                  const float* __restrict__ wp,
                  unsigned short* __restrict__ wpH,
                  unsigned short* __restrict__ wpL)
{
  if (blockIdx.x < 2048) {
    const int gw   = blockIdx.x * 4 + (threadIdx.x >> 6);  // 0..8191
    const int lane = threadIdx.x & 63;                     // = d
    const int bh   = gw >> 8;
    const int oct  = gw & 255;
    const int b = bh >> 4, h = bh & 15;
    const int tok0 = oct * 8;
    union { unsigned short u[8]; uint4 v; } ph;
    #pragma unroll
    for (int e = 0; e < 8; ++e) {
      const size_t g = (size_t)(b * kN + tok0 + e) * k3C + 2 * kC + h * kD + lane;
      ph.u[e] = H[g];
    }
    *(uint4*)(&VTH[((size_t)bh * kD + lane) * kN + tok0]) = ph.v;
  } else {
    const int i = (blockIdx.x - 2048) * 256 + threadIdx.x;  // < kWP/4 = 262144
    const float4 v = ((const float4*)wp)[i];
    ushort4 hh, ll;
    split4(v, hh, ll);
    ((ushort4*)wpH)[i] = hh;
    ((ushort4*)wpL)[i] = ll;
  }
}

// ============================================================================
// QKV GEMM, 256x192 tile -> grid 16x16 = 256 blocks = FULL CU coverage.
// 8 waves stacked in M (wave tile 32x192). Term-split 3-phase counted-vmcnt
// schedule with dual per-wave-group ledgers (verified round 10, ~1000 TF exec).
// ============================================================================
__global__ __launch_bounds__(512)
void gemm_qkv256(const unsigned short* __restrict__ AH,
                 const unsigned short* __restrict__ AL,
                 const unsigned short* __restrict__ WH,
                 const unsigned short* __restrict__ WL,
                 const float* __restrict__ bias,
                 unsigned short* __restrict__ OutH,
                 unsigned short* __restrict__ OutL,
                 const float* __restrict__ qn,
                 const float* __restrict__ kn)
{
  constexpr int BK = 32;
  constexpr int NT = kC / BK;   // 32 K-tiles

  // A: [buf][pl][256x32] = 64 KiB ; B: [buf][pl][192x32] = 48 KiB ; 112 total
  __shared__ __align__(16) unsigned short sA[2][2][256 * 32];
  __shared__ __align__(16) unsigned short sB[2][2][192 * 32];

  const int tt   = threadIdx.x;        // 0..511
  const int wave = tt >> 6;            // 0..7
  const int lane = tt & 63;
  const int quad = lane >> 4;
  const int l16  = lane & 15;
  const int bm = blockIdx.x * 256;
  const int bn = blockIdx.y * 192;
  const int wm = wave * 32;            // 8 waves stacked in M
  const bool wstg = (wave < 6);        // waves 0-5 stage W units

  // A staging: unit u = r*512 + tt; row = u>>2; swizzled col-group
  int srow[2], scol[2];
  #pragma unroll
  for (int r = 0; r < 2; ++r) {
    const int u = r * 512 + tt;
    srow[r] = u >> 2;
    scol[r] = ((u & 3) ^ ((srow[r] >> 1) & 3)) * 8;
  }
  // W staging: chunk c = r*384 + tt (tt<384); row = c>>2
  int wrow[2], wcol[2];
  #pragma unroll
  for (int r = 0; r < 2; ++r) {
    const int c = r * 384 + tt;
    wrow[r] = c >> 2;
    wcol[r] = ((c & 3) ^ ((wrow[r] >> 1) & 3)) * 8;
  }

  auto stageA = [&](int bf, int k0, int pl) {   // pl 0=hi 1=lo
    const unsigned short* src = pl ? AL : AH;
    #pragma unroll
    for (int r = 0; r < 2; ++r)
      glds16(&src[(size_t)(bm + srow[r]) * kC + k0 + scol[r]],
             &sA[bf][pl][(r * 512 + tt) * 8]);
  };
  auto stageW = [&](int bf, int k0, int pl) {
    if (!wstg) return;
    const unsigned short* src = pl ? WL : WH;
    #pragma unroll
    for (int r = 0; r < 2; ++r)
      glds16(&src[(size_t)(bn + wrow[r]) * kC + k0 + wcol[r]],
             &sB[bf][pl][(r * 384 + tt) * 8]);
  };

  auto rdA = [&](int bf, int pl, int row) -> bhalf8 {
    return *(const bhalf8*)(&sA[bf][pl][row * 32 + ((quad ^ ((row >> 1) & 3)) * 8)]);
  };
  auto rdB = [&](int bf, int pl, int row) -> bhalf8 {
    return *(const bhalf8*)(&sB[bf][pl][row * 32 + ((quad ^ ((row >> 1) & 3)) * 8)]);
  };

  f32x4 acc[2][12] = {};
  bhalf8 ah[2], al[2], b4[4];

  // ---- prologue: stage tile 0 ----
  stageA(0, 0, 0);          // AH0 (2)
  stageW(0, 0, 0);          // WH0 (2, waves 0-5)
  stageW(0, 0, 1);          // WL0 (2, waves 0-5)
  stageA(0, 0, 1);          // AL0 (2)
  if (wstg) { asm volatile("s_waitcnt vmcnt(4)" ::: "memory"); }   // drain AH0,WH0
  else      { asm volatile("s_waitcnt vmcnt(2)" ::: "memory"); }   // drain AH0
  __builtin_amdgcn_sched_barrier(0);
  asm volatile("s_barrier" ::: "memory");

  for (int t = 0; t < NT - 1; ++t) {
    const int buf  = t & 1;
    const int nbuf = buf ^ 1;
    const int nk0  = (t + 1) * BK;

    // ---- P01: hh term ----
    ah[0] = rdA(buf, 0, wm + l16);
    ah[1] = rdA(buf, 0, wm + 16 + l16);
    stageA(nbuf, nk0, 0);                 // AH(t+1)
    stageW(nbuf, nk0, 0);                 // WH(t+1)
    if (wstg) asm volatile("s_waitcnt vmcnt(6)" ::: "memory");   // drain WL(t)
    __builtin_amdgcn_sched_barrier(0);
    asm volatile("s_barrier" ::: "memory");
    __builtin_amdgcn_s_setprio(1);
    #pragma unroll
    for (int jj = 0; jj < 3; ++jj) {
      #pragma unroll
      for (int j = 0; j < 4; ++j) b4[j] = rdB(buf, 0, jj * 64 + j * 16 + l16);
      #pragma unroll
      for (int i = 0; i < 2; ++i)
        #pragma unroll
        for (int j = 0; j < 4; ++j)
          acc[i][jj * 4 + j] = __builtin_amdgcn_mfma_f32_16x16x32_bf16(ah[i], b4[j], acc[i][jj * 4 + j], 0, 0, 0);
    }
    __builtin_amdgcn_s_setprio(0);

    // ---- P2: hl term ----
    stageW(nbuf, nk0, 1);                 // WL(t+1)
    if (wstg) asm volatile("s_waitcnt vmcnt(6)" ::: "memory");   // drain AL(t)
    __builtin_amdgcn_sched_barrier(0);
    asm volatile("s_barrier" ::: "memory");
    __builtin_amdgcn_s_setprio(1);
    #pragma unroll
    for (int jj = 0; jj < 3; ++jj) {
      #pragma unroll
      for (int j = 0; j < 4; ++j) b4[j] = rdB(buf, 1, jj * 64 + j * 16 + l16);
      #pragma unroll
      for (int i = 0; i < 2; ++i)
        #pragma unroll
        for (int j = 0; j < 4; ++j)
          acc[i][jj * 4 + j] = __builtin_amdgcn_mfma_f32_16x16x32_bf16(ah[i], b4[j], acc[i][jj * 4 + j], 0, 0, 0);
    }
    __builtin_amdgcn_s_setprio(0);

    // ---- P3: lh term ----
    stageA(nbuf, nk0, 1);                 // AL(t+1)
    if (wstg) { asm volatile("s_waitcnt vmcnt(4)" ::: "memory"); }  // drain AH,WH(t+1)
    else      { asm volatile("s_waitcnt vmcnt(2)" ::: "memory"); }  // drain AL(t)+AH(t+1)
    __builtin_amdgcn_sched_barrier(0);
    asm volatile("s_barrier" ::: "memory");
    __builtin_amdgcn_s_setprio(1);
    al[0] = rdA(buf, 1, wm + l16);
    al[1] = rdA(buf, 1, wm + 16 + l16);
    #pragma unroll
    for (int jj = 0; jj < 3; ++jj) {
      #pragma unroll
      for (int j = 0; j < 4; ++j) b4[j] = rdB(buf, 0, jj * 64 + j * 16 + l16);
      #pragma unroll
      for (int i = 0; i < 2; ++i)
        #pragma unroll
        for (int j = 0; j < 4; ++j)
          acc[i][jj * 4 + j] = __builtin_amdgcn_mfma_f32_16x16x32_bf16(al[i], b4[j], acc[i][jj * 4 + j], 0, 0, 0);
    }
    __builtin_amdgcn_s_setprio(0);
    asm volatile("s_barrier" ::: "memory");   // end-of-tile lockstep
  }

  // ---- peeled last tile (no prefetch) ----
  {
    const int buf = (NT - 1) & 1;
    ah[0] = rdA(buf, 0, wm + l16);
    ah[1] = rdA(buf, 0, wm + 16 + l16);
    __builtin_amdgcn_s_setprio(1);
    #pragma unroll
    for (int jj = 0; jj < 3; ++jj) {
      #pragma unroll
      for (int j = 0; j < 4; ++j) b4[j] = rdB(buf, 0, jj * 64 + j * 16 + l16);
      #pragma unroll
      for (int i = 0; i < 2; ++i)
        #pragma unroll
        for (int j = 0; j < 4; ++j)
          acc[i][jj * 4 + j] = __builtin_amdgcn_mfma_f32_16x16x32_bf16(ah[i], b4[j], acc[i][jj * 4 + j], 0, 0, 0);
    }
    __builtin_amdgcn_s_setprio(0);

    if (wstg) asm volatile("s_waitcnt vmcnt(2)" ::: "memory");   // drain WL(last)
    __builtin_amdgcn_sched_barrier(0);
    asm volatile("s_barrier" ::: "memory");
    __builtin_amdgcn_s_setprio(1);
    #pragma unroll
    for (int jj = 0; jj < 3; ++jj) {
      #pragma unroll
      for (int j = 0; j < 4; ++j) b4[j] = rdB(buf, 1, jj * 64 + j * 16 + l16);
      #pragma unroll
      for (int i = 0; i < 2; ++i)
        #pragma unroll
        for (int j = 0; j < 4; ++j)
          acc[i][jj * 4 + j] = __builtin_amdgcn_mfma_f32_16x16x32_bf16(ah[i], b4[j], acc[i][jj * 4 + j], 0, 0, 0);
    }
    __builtin_amdgcn_s_setprio(0);

    asm volatile("s_waitcnt vmcnt(0)" ::: "memory");   // drain AL(last), both groups
    __builtin_amdgcn_sched_barrier(0);
    asm volatile("s_barrier" ::: "memory");
    __builtin_amdgcn_s_setprio(1);
    al[0] = rdA(buf, 1, wm + l16);
    al[1] = rdA(buf, 1, wm + 16 + l16);
    #pragma unroll
    for (int jj = 0; jj < 3; ++jj) {
      #pragma unroll
      for (int j = 0; j < 4; ++j) b4[j] = rdB(buf, 0, jj * 64 + j * 16 + l16);
      #pragma unroll
      for (int i = 0; i < 2; ++i)
        #pragma unroll
        for (int j = 0; j < 4; ++j)
          acc[i][jj * 4 + j] = __builtin_amdgcn_mfma_f32_16x16x32_bf16(al[i], b4[j], acc[i][jj * 4 + j], 0, 0, 0);
    }
    __builtin_amdgcn_s_setprio(0);
  }

  // epilogue: per-head (jj) slice logic; C/D layout col=lane&15, row=quad*4+r
  #pragma unroll
  for (int i = 0; i < 2; ++i) {
    #pragma unroll
    for (int jj = 0; jj < 3; ++jj) {
      const int n0 = bn + jj * 64;       // head-aligned; heads never cross slices
      const int slice = n0 >> 10;        // 0=q,1=k,2=v
      const bool writeL = (slice == 0);
      float val[4][4], wv[4];
      #pragma unroll
      for (int u = 0; u < 4; ++u) {
        const float bv = bias[n0 + u * 16 + l16];
        #pragma unroll
        for (int r = 0; r < 4; ++r) val[u][r] = acc[i][jj * 4 + u][r] + bv;
        if (slice < 2) wv[u] = (slice ? kn : qn)[u * 16 + l16];  // d = u*16+l16
      }

      if (slice < 2) {
        #pragma unroll
        for (int r = 0; r < 4; ++r) {
          float ss = val[0][r] * val[0][r];
          #pragma unroll
          for (int u = 1; u < 4; ++u) ss += val[u][r] * val[u][r];
          #pragma unroll
          for (int d = 1; d < 16; d <<= 1) ss += __shfl_xor(ss, d, 64);
          float rinv = rsqrtf(ss * (1.0f / 64.0f) + 1e-6f);
          // q * D^-0.5 * log2(e): attn uses hardware 2^x
          if (slice == 0) rinv *= 0.18033688011112042f;
          #pragma unroll
          for (int u = 0; u < 4; ++u) val[u][r] = wv[u] * (val[u][r] * rinv);
        }
      }

      #pragma unroll
      for (int u = 0; u < 4; ++u) {
        const int n = n0 + u * 16 + l16;
        #pragma unroll
        for (int r = 0; r < 4; ++r) {
          const int m = bm + wm + i * 16 + quad * 4 + r;
          unsigned short hh, ll;
          split2(val[u][r], hh, ll);
          OutH[(size_t)m * k3C + n] = hh;
          if (writeL) OutL[(size_t)m * k3C + n] = ll;
        }
      }
    }
  }
}

// ============================================================================
// PROJ GEMM, 128x128 tile, 4 waves (2x2), BK=32 — term-split 3-phase schedule
// (verified round 9). A stride = k3C (q-slice), fp32 out + bias.
// ============================================================================
__global__ __launch_bounds__(256)
void gemm_proj128(const unsigned short* __restrict__ AH,
                  const unsigned short* __restrict__ AL,
                  const unsigned short* __restrict__ WH,
                  const unsigned short* __restrict__ WL,
                  const float* __restrict__ bias,
                  float* __restrict__ Out)
{
  constexpr int BK = 32;
  constexpr int NT = kC / BK;   // 32 K-tiles

  __shared__ __align__(16) unsigned short sA[2][2][128 * 32];
  __shared__ __align__(16) unsigned short sB[2][2][128 * 32];

  const int tt   = threadIdx.x;        // 0..255
  const int wave = tt >> 6;            // 0..3
  const int lane = tt & 63;
  const int quad = lane >> 4;
  const int l16  = lane & 15;
  const int bm = blockIdx.x * 128;
  const int bn = blockIdx.y * 128;
  const int wm = (wave >> 1) * 64;     // wave row: 0/64
  const int wn = (wave & 1) * 64;      // wave col: 0/64

  int srow[2], scol[2];
  #pragma unroll
  for (int r = 0; r < 2; ++r) {
    const int c = r * 256 + tt;
    srow[r] = c >> 2;
    scol[r] = ((c & 3) ^ ((srow[r] >> 1) & 3)) * 8;
  }

  // unit: 0=AH 1=WH 2=WL 3=AL (issue order!); A stride k3C, W stride kC
  auto stageU = [&](int bf, int k0, int which) {
    const unsigned short* src = (which == 0) ? AH : (which == 1) ? WH
                              : (which == 2) ? WL : AL;
    const bool isA = (which == 0 || which == 3);
    const int base = isA ? bm : bn;
    const int ld   = isA ? k3C : kC;
    unsigned short* dst = (which == 0) ? &sA[bf][0][0]
                        : (which == 3) ? &sA[bf][1][0]
                        : (which == 1) ? &sB[bf][0][0] : &sB[bf][1][0];
    #pragma unroll
    for (int r = 0; r < 2; ++r)
      glds16(&src[(size_t)(base + srow[r]) * ld + k0 + scol[r]],
             &dst[(r * 256 + tt) * 8]);
  };

  auto rdA = [&](int bf, int pl, int row) -> bhalf8 {
    return *(const bhalf8*)(&sA[bf][pl][row * 32 + ((quad ^ ((row >> 1) & 3)) * 8)]);
  };
  auto rdB = [&](int bf, int pl, int row) -> bhalf8 {
    return *(const bhalf8*)(&sB[bf][pl][row * 32 + ((quad ^ ((row >> 1) & 3)) * 8)]);
  };

  f32x4 acc[4][4] = {};
  bhalf8 ah[4], bh_[4], bl_[4];

  stageU(0, 0, 0); stageU(0, 0, 1); stageU(0, 0, 2); stageU(0, 0, 3);
  asm volatile("s_waitcnt vmcnt(4)" ::: "memory");
  __builtin_amdgcn_sched_barrier(0);
  asm volatile("s_barrier" ::: "memory");

  for (int t = 0; t < NT - 1; ++t) {
    const int buf  = t & 1;
    const int nbuf = buf ^ 1;
    const int nk0  = (t + 1) * BK;

    // ---- P01: hh ----
    #pragma unroll
    for (int i = 0; i < 4; ++i) ah[i]  = rdA(buf, 0, wm + i * 16 + l16);
    #pragma unroll
    for (int j = 0; j < 4; ++j) bh_[j] = rdB(buf, 0, wn + j * 16 + l16);
    stageU(nbuf, nk0, 0);
    stageU(nbuf, nk0, 1);
    asm volatile("s_waitcnt vmcnt(6)" ::: "memory");
    __builtin_amdgcn_sched_barrier(0);
    asm volatile("s_barrier" ::: "memory");
    __builtin_amdgcn_s_setprio(1);
    #pragma unroll
    for (int i = 0; i < 4; ++i)
      #pragma unroll
      for (int j = 0; j < 4; ++j)
        acc[i][j] = __builtin_amdgcn_mfma_f32_16x16x32_bf16(ah[i], bh_[j], acc[i][j], 0, 0, 0);
    __builtin_amdgcn_s_setprio(0);

    // ---- P2: hl ----
    #pragma unroll
    for (int j = 0; j < 4; ++j) bl_[j] = rdB(buf, 1, wn + j * 16 + l16);
    stageU(nbuf, nk0, 2);
    asm volatile("s_waitcnt vmcnt(6)" ::: "memory");
    __builtin_amdgcn_sched_barrier(0);
    asm volatile("s_barrier" ::: "memory");
    __builtin_amdgcn_s_setprio(1);
    #pragma unroll
    for (int i = 0; i < 4; ++i)
      #pragma unroll
      for (int j = 0; j < 4; ++j)
        acc[i][j] = __builtin_amdgcn_mfma_f32_16x16x32_bf16(ah[i], bl_[j], acc[i][j], 0, 0, 0);
    __builtin_amdgcn_s_setprio(0);

    // ---- P3: lh ----
    stageU(nbuf, nk0, 3);
    asm volatile("s_waitcnt vmcnt(4)" ::: "memory");
    __builtin_amdgcn_sched_barrier(0);
    asm volatile("s_barrier" ::: "memory");
    __builtin_amdgcn_s_setprio(1);
    {
      bhalf8 al0[4];
      #pragma unroll
      for (int i = 0; i < 4; ++i) al0[i] = rdA(buf, 1, wm + i * 16 + l16);
      #pragma unroll
      for (int i = 0; i < 4; ++i)
        #pragma unroll
        for (int j = 0; j < 4; ++j)
          acc[i][j] = __builtin_amdgcn_mfma_f32_16x16x32_bf16(al0[i], bh_[j], acc[i][j], 0, 0, 0);
    }
    __builtin_amdgcn_s_setprio(0);
    asm volatile("s_barrier" ::: "memory");
  }

  {
    const int buf = (NT - 1) & 1;
    #pragma unroll
    for (int i = 0; i < 4; ++i) ah[i]  = rdA(buf, 0, wm + i * 16 + l16);
    #pragma unroll
    for (int j = 0; j < 4; ++j) bh_[j] = rdB(buf, 0, wn + j * 16 + l16);
    __builtin_amdgcn_s_setprio(1);
    #pragma unroll
    for (int i = 0; i < 4; ++i)
      #pragma unroll
      for (int j = 0; j < 4; ++j)
        acc[i][j] = __builtin_amdgcn_mfma_f32_16x16x32_bf16(ah[i], bh_[j], acc[i][j], 0, 0, 0);
    __builtin_amdgcn_s_setprio(0);

    asm volatile("s_waitcnt vmcnt(2)" ::: "memory");
    __builtin_amdgcn_sched_barrier(0);
    asm volatile("s_barrier" ::: "memory");
    #pragma unroll
    for (int j = 0; j < 4; ++j) bl_[j] = rdB(buf, 1, wn + j * 16 + l16);
    __builtin_amdgcn_s_setprio(1);
    #pragma unroll
    for (int i = 0; i < 4; ++i)
      #pragma unroll
      for (int j = 0; j < 4; ++j)
        acc[i][j] = __builtin_amdgcn_mfma_f32_16x16x32_bf16(ah[i], bl_[j], acc[i][j], 0, 0, 0);
    __builtin_amdgcn_s_setprio(0);

    asm volatile("s_waitcnt vmcnt(0)" ::: "memory");
    __builtin_amdgcn_sched_barrier(0);
    asm volatile("s_barrier" ::: "memory");
    __builtin_amdgcn_s_setprio(1);
    {
      bhalf8 al0[4];
      #pragma unroll
      for (int i = 0; i < 4; ++i) al0[i] = rdA(buf, 1, wm + i * 16 + l16);
      #pragma unroll
      for (int i = 0; i < 4; ++i)
        #pragma unroll
        for (int j = 0; j < 4; ++j)
          acc[i][j] = __builtin_amdgcn_mfma_f32_16x16x32_bf16(al0[i], bh_[j], acc[i][j], 0, 0, 0);
    }
    __builtin_amdgcn_s_setprio(0);
  }

  float bv[4];
  #pragma unroll
  for (int j = 0; j < 4; ++j) bv[j] = bias[bn + wn + j * 16 + l16];

  #pragma unroll
  for (int i = 0; i < 4; ++i)
    #pragma unroll
    for (int j = 0; j < 4; ++j) {
      const int n = bn + wn + j * 16 + l16;
      #pragma unroll
      for (int r = 0; r < 4; ++r) {
        const int m = bm + wm + i * 16 + quad * 4 + r;
        Out[(size_t)m * kC + n] = acc[i][j][r] + bv[j];
      }
    }
}

// ---- flash attention v12: round-10 structure (dbuf K/V, one barrier/iter,
// Pt pitch 68, hw exp2) + HALF-SPLIT interleave: PV(kk=0) issues right after
// key-groups 0-1's exp/store, overlapping with key-groups 2-3's QK/exp
// (partial lgkmcnt instead of a full drain). FP accumulation order per
// accumulator is UNCHANGED (nt ascending; kk=0 before kk=1) -> bit-identical.
// + T5 setprio around MFMA clusters (m191: +4-7% attn). ----
__global__ __launch_bounds__(256)
void attn_kernel(unsigned short* __restrict__ H, unsigned short* __restrict__ L,
                 const unsigned short* __restrict__ VTH,
                 const int* __restrict__ mask)
{
  constexpr int P   = 72;  // K/V pitch: bank-start 4*((row+col16)%8) — balanced
  constexpr int Ppt = 68;  // Pt pitch: quad groups land on distinct banks
  __shared__ __align__(16) unsigned short KtH[2][64 * P];   // 18.4 KB dbuf
  __shared__ __align__(16) unsigned short VtH[2][64 * P];   // 18.4 KB dbuf
  __shared__ __align__(16) unsigned short Pt[4][32 * Ppt];  // 17.4 KB per-wave

  const int t    = threadIdx.x;
  const int wave = t >> 6;
  const int lane = t & 63;
  const int quad = lane >> 4;
  const int l16  = lane & 15;

  // XCD swizzle: lin%8 = XCD (dispatch round-robin); 4 bh per XCD.
  const int lin  = blockIdx.x;          // 0..511
  const int xcd  = lin & 7;
  const int slot = lin >> 3;            // 0..63
  const int bh   = xcd + 8 * (slot >> 4);
  const int qblk = slot & 15;
  const int b  = bh >> 4;
  const int h  = bh & 15;
  const int q0 = qblk * 128 + wave * 32;  // 32 q-rows/wave

  // staging geometry: 2 chunks of 8 u16 per thread per tile
  const int row0 = t >> 3,         col0 = (t & 7) * 8;
  const int row1 = (256 + t) >> 3, col1 = ((256 + t) & 7) * 8;

  // Q fragments, both groups (A-layout: m=l16, k=quad*8+j)
  bhalf8 qfh[2][2], qfl[2][2];
  #pragma unroll
  for (int g = 0; g < 2; ++g) {
    const size_t qrow = (size_t)(b * kN + q0 + g * 16 + l16) * k3C + h * kD;
    qfh[g][0] = *(const bhalf8*)(&H[qrow + quad * 8]);
    qfh[g][1] = *(const bhalf8*)(&H[qrow + 32 + quad * 8]);
    qfl[g][0] = *(const bhalf8*)(&L[qrow + quad * 8]);
    qfl[g][1] = *(const bhalf8*)(&L[qrow + 32 + quad * 8]);
  }

  f32x4 acc_o[2][4] = {};
  float lpart[2][4] = {};

  uint4 sk0, sk1, sv0, sv1;            // staging regs
  int mcur[4], mnext[4];

  auto pref = [&](int kt) {
    sk0 = *(const uint4*)(&H[(size_t)(b * kN + kt + row0) * k3C + kC + h * kD + col0]);
    sk1 = *(const uint4*)(&H[(size_t)(b * kN + kt + row1) * k3C + kC + h * kD + col1]);
    sv0 = *(const uint4*)(&VTH[((size_t)bh * kD + row0) * kN + kt + col0]);
    sv1 = *(const uint4*)(&VTH[((size_t)bh * kD + row1) * kN + kt + col1]);
  };
  auto store_tile = [&](int bf) {
    *(uint4*)(&KtH[bf][row0 * P + col0]) = sk0;
    *(uint4*)(&KtH[bf][row1 * P + col1]) = sk1;
    *(uint4*)(&VtH[bf][row0 * P + col0]) = sv0;
    *(uint4*)(&VtH[bf][row1 * P + col1]) = sv1;
  };
  auto loadM = [&](int kt, int* m) {
    #pragma unroll
    for (int nt = 0; nt < 4; ++nt) m[nt] = mask[b * kN + kt + nt * 16 + l16];
  };

  // prologue: tile 0 -> buf0; issue tile 1 loads; one barrier
  pref(0);
  loadM(0, mcur);
  #pragma unroll
  for (int nt = 0; nt < 4; ++nt) mnext[nt] = mcur[nt];
  store_tile(0);                       // compiler inserts vmcnt for sk/sv deps
  pref(64);                            // tile 1 in flight across the barrier
  __syncthreads();

  for (int i = 0; i < 32; ++i) {
    const int cur = i & 1;
    const int kt = i * 64;
    if (i < 31) loadM(kt + 64, mnext);

    #pragma unroll
    for (int hf = 0; hf < 2; ++hf) {
      // ---- QK^T for this half's two key-groups; p = flag*2^s -> Pt ----
      #pragma unroll
      for (int nt2 = 0; nt2 < 2; ++nt2) {
        const int nt = hf * 2 + nt2;
        const int kr = (nt * 16 + l16) * P + quad * 8;
        const bhalf8 kh0 = *(const bhalf8*)(&KtH[cur][kr]);
        const bhalf8 kh1 = *(const bhalf8*)(&KtH[cur][kr + 32]);
        const float flag = mcur[nt] ? 1.0f : 0.0f;
        #pragma unroll
        for (int g = 0; g < 2; ++g) {
          f32x4 s = {};
          __builtin_amdgcn_s_setprio(1);
          s = __builtin_amdgcn_mfma_f32_16x16x32_bf16(qfh[g][0], kh0, s, 0, 0, 0);
          s = __builtin_amdgcn_mfma_f32_16x16x32_bf16(qfh[g][1], kh1, s, 0, 0, 0);
          s = __builtin_amdgcn_mfma_f32_16x16x32_bf16(qfl[g][0], kh0, s, 0, 0, 0);
          s = __builtin_amdgcn_mfma_f32_16x16x32_bf16(qfl[g][1], kh1, s, 0, 0, 0);
          __builtin_amdgcn_s_setprio(0);
          #pragma unroll
          for (int r = 0; r < 4; ++r) {
            const float p = flag * fexp2(s[r]);   // s pre-scaled by log2e
            lpart[g][r] += p;
            Pt[wave][(g * 16 + quad * 4 + r) * Ppt + nt * 16 + l16] = f2bf(p);
          }
        }
      }

      // ---- PV for kk = hf (needs only this half's Pt columns) ----
      const int kk = hf;
      const bhalf8 pa0 = *(const bhalf8*)(&Pt[wave][l16 * Ppt + kk * 32 + quad * 8]);
      const bhalf8 pa1 = *(const bhalf8*)(&Pt[wave][(16 + l16) * Ppt + kk * 32 + quad * 8]);
      __builtin_amdgcn_s_setprio(1);
      #pragma unroll
      for (int dt = 0; dt < 4; ++dt) {
        const bhalf8 vb = *(const bhalf8*)(&VtH[cur][(dt * 16 + l16) * P + kk * 32 + quad * 8]);
        acc_o[0][dt] = __builtin_amdgcn_mfma_f32_16x16x32_bf16(pa0, vb, acc_o[0][dt], 0, 0, 0);
        acc_o[1][dt] = __builtin_amdgcn_mfma_f32_16x16x32_bf16(pa1, vb, acc_o[1][dt], 0, 0, 0);
      }
      __builtin_amdgcn_s_setprio(0);
    }

    if (i < 31) {
      store_tile(cur ^ 1);             // tile i+1 into the other buffer
      if (i < 30) pref(kt + 128);      // tile i+2 in flight across barrier
      __syncthreads();                 // single barrier per iteration
      #pragma unroll
      for (int nt = 0; nt < 4; ++nt) mcur[nt] = mnext[nt];
    }
  }

  // final l reduction + normalize + store hi/lo into q-slice
  #pragma unroll
  for (int g = 0; g < 2; ++g)
    #pragma unroll
    for (int r = 0; r < 4; ++r) {
      float s = lpart[g][r];
      #pragma unroll
      for (int d = 1; d < 16; d <<= 1) s += __shfl_xor(s, d, 64);
      lpart[g][r] = s;
    }
  #pragma unroll
  for (int g = 0; g < 2; ++g)
    #pragma unroll
    for (int dt = 0; dt < 4; ++dt)
      #pragma unroll
      for (int r = 0; r < 4; ++r) {
        const int qrow = q0 + g * 16 + quad * 4 + r;
        const float inv = 1.0f / fmaxf(lpart[g][r], 1.0e-30f);
        const size_t off = (size_t)(b * kN + qrow) * k3C + h * kD + dt * 16 + l16;
        unsigned short hh, ll;
        split2(acc_o[g][dt][r] * inv, hh, ll);
        H[off] = hh; L[off] = ll;
      }
}

} // anonymous namespace

extern "C" void kernel_launch(void* const* d_in, const int* in_sizes, int n_in,
                              void* d_out, int out_size, void* d_ws, size_t ws_size,
                              hipStream_t stream)
{
  const float* x      = (const float*)d_in[0];
  const int*   maskp  = (const int*)d_in[1];
  const float* qkv_w  = (const float*)d_in[2];
  const float* qkv_b  = (const float*)d_in[3];
  const float* proj_w = (const float*)d_in[4];
  const float* proj_b = (const float*)d_in[5];
  const float* qn_w   = (const float*)d_in[6];
  const float* kn_w   = (const float*)d_in[7];
  float* out = (float*)d_out;

  unsigned short* qH = (unsigned short*)d_ws;      // qkv hi plane
  unsigned short* qL = qH + kPS;                   // qkv lo plane
  unsigned short* R1 = qL + kPS;                   // x planes -> later VT plane
  unsigned short* R2 = R1 + 2 * kXE;               // qkv_w planes -> later proj_w planes
  unsigned short* xH = R1,  *xL = R1 + kXE;
  unsigned short* VTH = R1;                        // reuse after gemm1
  unsigned short* wqH = R2, *wqL = R2 + kWQ;
  unsigned short* wpH = R2, *wpL = R2 + kWP;

  // 1) fused prep: split x + qkv_w (one launch; 4096 + 3072 blocks)
  prep_split<<<(int)((kXE + kWQ) / 4 / 256), 256, 0, stream>>>(
      x, qkv_w, xH, xL, wqH, wqL);

  // 2) qkv = x @ qkv_w^T + qkv_b, RMSNorm(q,k) fused; grid 16x16 = 256 blocks
  gemm_qkv256<<<dim3(kTok / 256, k3C / 192), 512, 0, stream>>>(
      xH, xL, wqH, wqL, qkv_b, qH, qL, qn_w, kn_w);

  // 3) fused: V^T pre-transpose (2048 blocks) + proj_w split (1024 blocks)
  vt_and_split<<<3072, 256, 0, stream>>>(qH, VTH, proj_w, wpH, wpL);

  // 4) masked flash attention (XCD-swizzled 1-D grid, 512 blocks)
  attn_kernel<<<dim3(512), 256, 0, stream>>>(qH, qL, VTH, maskp);

  // 5) out = attn @ proj_w^T + proj_b  (term-split 3-phase, grid 32x8=256)
  gemm_proj128<<<dim3(kTok / 128, kC / 128), 256, 0, stream>>>(
      qH, qL, wpH, wpL, proj_b, out);
}